// Round 2
// baseline (9589.037 us; speedup 1.0000x reference)
//
#include <hip/hip_runtime.h>
#include <cstdint>
#include <cstddef>

#define Bdim 256
#define Ndim 96
#define Edim 1024
#define HDdim 300
#define Ldim 2
#define LHdim 600
#define NCdim 7
#define GDdim 900              // HD*(L+1)
#define ROWS (Bdim*Ndim)       // 24576

// Identity row-perm constants for gemm_tn
#define IDP 0x7FFFFFFF, 1, 30, 0, 0

// ---------------------------------------------------------------------------
// Generic fp32 GEMM: C[m,n] = act( sum_k A[rowA(m),k]*W[n,k] + b1[n] + b2[n] (+C) )
// rowA(m) = (m & pmask)*pmul1 + (m >> pshift)*pmul2 + padd   (A-row permutation)
// A: (M,K) rows per perm, lda; W: (N,K) row-major ldw (computes A @ W^T)
// ACT: 0 none, 1 prelu(aptr). ACC: 1 -> C += result.
// ---------------------------------------------------------------------------
template<int ACT, int ACC>
__global__ __launch_bounds__(256) void gemm_tn(
    const float* __restrict__ A, int lda,
    int pmask, int pmul1, int pshift, int pmul2, int padd,
    const float* __restrict__ W, int ldw,
    float* __restrict__ C, int ldc,
    int M, int Nd, int K,
    const float* __restrict__ bias1,
    const float* __restrict__ bias2,
    const float* __restrict__ aptr)
{
    __shared__ __align__(16) float As[16][68];
    __shared__ __align__(16) float Ws[16][68];
    const int bm = blockIdx.x * 64;
    const int bn = blockIdx.y * 64;
    const int tid = threadIdx.x;
    const int lm  = tid & 63;          // row within tile for loading
    const int lk4 = (tid >> 6) << 2;   // k sub-offset: 0,4,8,12
    const int tm = (tid >> 4) << 2;    // 0..60
    const int tn = (tid & 15) << 2;    // 0..60
    float acc[4][4] = {{0.f,0.f,0.f,0.f},{0.f,0.f,0.f,0.f},{0.f,0.f,0.f,0.f},{0.f,0.f,0.f,0.f}};
    const int am = bm + lm;
    const int wn = bn + lm;
    const int rowA = (am & pmask) * pmul1 + (am >> pshift) * pmul2 + padd;

    for (int k0 = 0; k0 < K; k0 += 16) {
        float4 av, wv;
        const bool fullk = (k0 + 16 <= K);
        if (fullk) {
            av = (am < M)  ? *(const float4*)(A + (size_t)rowA * lda + k0 + lk4) : make_float4(0.f,0.f,0.f,0.f);
            wv = (wn < Nd) ? *(const float4*)(W + (size_t)wn   * ldw + k0 + lk4) : make_float4(0.f,0.f,0.f,0.f);
        } else {
            float ta[4], tw[4];
            #pragma unroll
            for (int u = 0; u < 4; ++u) {
                int k = k0 + lk4 + u;
                ta[u] = (am < M  && k < K) ? A[(size_t)rowA * lda + k] : 0.f;
                tw[u] = (wn < Nd && k < K) ? W[(size_t)wn   * ldw + k] : 0.f;
            }
            av = make_float4(ta[0],ta[1],ta[2],ta[3]);
            wv = make_float4(tw[0],tw[1],tw[2],tw[3]);
        }
        __syncthreads();   // protect previous iteration's LDS reads
        As[lk4+0][lm] = av.x; As[lk4+1][lm] = av.y; As[lk4+2][lm] = av.z; As[lk4+3][lm] = av.w;
        Ws[lk4+0][lm] = wv.x; Ws[lk4+1][lm] = wv.y; Ws[lk4+2][lm] = wv.z; Ws[lk4+3][lm] = wv.w;
        __syncthreads();
        #pragma unroll
        for (int kk = 0; kk < 16; ++kk) {
            float a0[4], w0[4];
            *(float4*)a0 = *(const float4*)&As[kk][tm];
            *(float4*)w0 = *(const float4*)&Ws[kk][tn];
            #pragma unroll
            for (int i = 0; i < 4; ++i)
                #pragma unroll
                for (int j = 0; j < 4; ++j)
                    acc[i][j] = fmaf(a0[i], w0[j], acc[i][j]);
        }
    }

    const float aval = (ACT == 1) ? *aptr : 0.f;
    #pragma unroll
    for (int i = 0; i < 4; ++i) {
        int m = bm + tm + i;
        if (m >= M) continue;
        #pragma unroll
        for (int j = 0; j < 4; ++j) {
            int n = bn + tn + j;
            if (n >= Nd) continue;
            float v = acc[i][j];
            if (bias1) v += bias1[n];
            if (bias2) v += bias2[n];
            if (ACC)   v += C[(size_t)m * ldc + n];
            if (ACT == 1) v = (v >= 0.f) ? v : aval * v;
            C[(size_t)m * ldc + n] = v;
        }
    }
}

// ---------------------------------------------------------------------------
// inv_norm[frow] = 1/(||features[frow,:]||+1e-8)  (b-major, same as features)
// ---------------------------------------------------------------------------
__global__ __launch_bounds__(256) void norm_kernel(const float* __restrict__ f, float* __restrict__ invn)
{
    int row  = blockIdx.x * 4 + (threadIdx.x >> 6);
    int lane = threadIdx.x & 63;
    const float* fr = f + (size_t)row * Edim;
    float ss = 0.f;
    for (int t = lane; t < Edim; t += 64) { float v = fr[t]; ss = fmaf(v, v, ss); }
    #pragma unroll
    for (int o = 32; o > 0; o >>= 1) ss += __shfl_down(ss, o);
    if (lane == 0) invn[row] = 1.f / (sqrtf(ss) + 1e-8f);
}

// ---------------------------------------------------------------------------
// Per-batch sim + adjacency (all b-major). Block = 256 threads, 6x6 out each.
// ---------------------------------------------------------------------------
__global__ __launch_bounds__(256) void simadj_kernel(
    const float* __restrict__ f, const float* __restrict__ invn,
    const float* __restrict__ entro, const float* __restrict__ alphap,
    const float* __restrict__ thrp, uint8_t* __restrict__ adj)
{
    int b = blockIdx.x;
    __shared__ float S[16][100];
    int tid = threadIdx.x;
    int i0 = (tid >> 4) * 6, j0 = (tid & 15) * 6;
    float acc[6][6];
    #pragma unroll
    for (int i = 0; i < 6; ++i)
        #pragma unroll
        for (int j = 0; j < 6; ++j) acc[i][j] = 0.f;
    const float* fb = f + (size_t)b * Ndim * Edim;

    for (int k0 = 0; k0 < Edim; k0 += 16) {
        __syncthreads();
        #pragma unroll
        for (int r = 0; r < 6; ++r) {
            int n = (tid >> 4) + r * 16;
            S[tid & 15][n] = fb[(size_t)n * Edim + k0 + (tid & 15)];
        }
        __syncthreads();
        #pragma unroll
        for (int kk = 0; kk < 16; ++kk) {
            float a[6], bb[6];
            #pragma unroll
            for (int u = 0; u < 6; ++u) a[u] = S[kk][i0 + u];
            #pragma unroll
            for (int u = 0; u < 6; ++u) bb[u] = S[kk][j0 + u];
            #pragma unroll
            for (int i = 0; i < 6; ++i)
                #pragma unroll
                for (int j = 0; j < 6; ++j)
                    acc[i][j] = fmaf(a[i], bb[j], acc[i][j]);
        }
    }

    float alpha = *alphap, thr = *thrp;
    float onem = 1.f - alpha;
    #pragma unroll
    for (int i = 0; i < 6; ++i) {
        int ii = i0 + i;
        float inv_i = invn[b * Ndim + ii];
        #pragma unroll
        for (int j = 0; j < 6; ++j) {
            int jj = j0 + j;
            float simv = acc[i][j] * inv_i * invn[b * Ndim + jj];
            float comb = alpha * entro[b * Ndim + jj] + onem * simv;
            adj[((size_t)b * Ndim + ii) * Ndim + jj] = (comb > thr) ? 1 : 0;
        }
    }
}

// ---------------------------------------------------------------------------
// q[r]=H[r,:300].wq; k[r]=H[r,:300].wk  (H n-major rows, stride 900)
// ---------------------------------------------------------------------------
__global__ __launch_bounds__(256) void qk_kernel(
    const float* __restrict__ Hsrc, const float* __restrict__ wqk,
    float* __restrict__ q, float* __restrict__ k)
{
    int row  = blockIdx.x * 4 + (threadIdx.x >> 6);
    int lane = threadIdx.x & 63;
    const float* h = Hsrc + (size_t)row * GDdim;
    float sq = 0.f, sk = 0.f;
    for (int t = lane; t < HDdim; t += 64) {
        float hv = h[t];
        sq = fmaf(hv, wqk[t], sq);
        sk = fmaf(hv, wqk[HDdim + t], sk);
    }
    #pragma unroll
    for (int o = 32; o > 0; o >>= 1) { sq += __shfl_down(sq, o); sk += __shfl_down(sk, o); }
    if (lane == 0) { q[row] = sq; k[row] = sk; }
}

// ---------------------------------------------------------------------------
// Fused masked softmax + dual-value aggregation. blockIdx = storage row
// r = i*256 + b (n-major). V0/V1 n-major. Mout row stride 900.
// ---------------------------------------------------------------------------
__global__ __launch_bounds__(128) void gat_attn_kernel(
    const float* __restrict__ q, const float* __restrict__ k,
    const uint8_t* __restrict__ adj, const int* __restrict__ smask,
    const float* __restrict__ V0, const float* __restrict__ V1,
    const float* __restrict__ gbp,
    float* __restrict__ Mout)
{
    int r  = blockIdx.x;                 // storage row: i*256+b
    int i  = r >> 8;
    int b  = r & 255;
    int tid = threadIdx.x;
    __shared__ float w[128];
    __shared__ float red[128];
    float gb = *gbp;
    float sc = -1.0e9f;
    if (tid < Ndim) {
        uint8_t a = adj[((size_t)b * Ndim + i) * Ndim + tid];
        sc = a ? (q[r] + k[tid * Bdim + b] + gb) : -1.0e9f;
    }
    red[tid] = sc;
    __syncthreads();
    #pragma unroll
    for (int s = 64; s > 0; s >>= 1) { if (tid < s) red[tid] = fmaxf(red[tid], red[tid + s]); __syncthreads(); }
    float m = red[0];
    __syncthreads();
    float e = (tid < Ndim) ? expf(sc - m) : 0.f;
    w[tid] = e;
    red[tid] = e;
    __syncthreads();
    #pragma unroll
    for (int s = 64; s > 0; s >>= 1) { if (tid < s) red[tid] += red[tid + s]; __syncthreads(); }
    float inv = 1.f / red[0];
    __syncthreads();

    float a0 = 0.f, a1 = 0.f, a2 = 0.f;
    const int* sm = smask + ((size_t)b * Ndim + i) * Ndim;
    for (int j = 0; j < Ndim; ++j) {
        float wj = w[j];
        if (wj == 0.f) continue;                      // uniform across block
        const float* V = (sm[j] ? V0 : V1) + (size_t)(j * Bdim + b) * HDdim;
        a0 = fmaf(wj, V[tid], a0);
        a1 = fmaf(wj, V[tid + 128], a1);
        if (tid < HDdim - 256) a2 = fmaf(wj, V[tid + 256], a2);
    }
    float* mo = Mout + (size_t)r * GDdim;
    mo[tid]       = a0 * inv;
    mo[tid + 128] = a1 * inv;
    if (tid < HDdim - 256) mo[tid + 256] = a2 * inv;
}

// ---------------------------------------------------------------------------
// zero h and c
// ---------------------------------------------------------------------------
__global__ __launch_bounds__(256) void zero_hc_kernel(float* __restrict__ h, float* __restrict__ c, int n)
{
    int i = blockIdx.x * 256 + threadIdx.x;
    if (i < n) { h[i] = 0.f; c[i] = 0.f; }
}

// ---------------------------------------------------------------------------
// LSTM cell: gates = G[b,:] + zt[b,:]; update h,c (b-major, B x 600); Hl[idx]=h
// ---------------------------------------------------------------------------
__global__ __launch_bounds__(256) void lstm_cell_kernel(
    const float* __restrict__ G, const float* __restrict__ zt,
    float* __restrict__ h, float* __restrict__ c,
    float* __restrict__ Hl)
{
    int idx = blockIdx.x * 256 + threadIdx.x;       // b*600+u
    if (idx >= Bdim * LHdim) return;
    int b = idx / LHdim, u = idx - b * LHdim;
    const float* g = G  + (size_t)b * (4 * LHdim);
    const float* z = zt + (size_t)b * (4 * LHdim);
    float gi = g[u]             + z[u];
    float gf = g[u + LHdim]     + z[u + LHdim];
    float gg = g[u + 2 * LHdim] + z[u + 2 * LHdim];
    float go = g[u + 3 * LHdim] + z[u + 3 * LHdim];
    float si = 1.f / (1.f + expf(-gi));
    float sf = 1.f / (1.f + expf(-gf));
    float so = 1.f / (1.f + expf(-go));
    float tg = tanhf(gg);
    float cn = sf * c[idx] + si * tg;
    float hn = so * tanhf(cn);
    c[idx] = cn;
    h[idx] = hn;
    Hl[idx] = hn;          // Hl pre-offset to row t*256
}

// ---------------------------------------------------------------------------
// Final head: x is n-major (r = n*256+b); out is b-major (b*96+n, 7)
// ---------------------------------------------------------------------------
__global__ __launch_bounds__(256) void out_kernel(
    const float* __restrict__ x, const float* __restrict__ ow,
    const float* __restrict__ ob, float* __restrict__ out)
{
    int r    = blockIdx.x * 4 + (threadIdx.x >> 6);
    int lane = threadIdx.x & 63;
    const float* xr = x + (size_t)r * HDdim;
    float acc[NCdim];
    #pragma unroll
    for (int n = 0; n < NCdim; ++n) acc[n] = 0.f;
    for (int t = lane; t < HDdim; t += 64) {
        float xv = xr[t];
        #pragma unroll
        for (int n = 0; n < NCdim; ++n) acc[n] = fmaf(xv, ow[n * HDdim + t], acc[n]);
    }
    #pragma unroll
    for (int o = 32; o > 0; o >>= 1)
        #pragma unroll
        for (int n = 0; n < NCdim; ++n) acc[n] += __shfl_down(acc[n], o);
    if (lane == 0) {
        int b = r & 255, nn = r >> 8;
        #pragma unroll
        for (int n = 0; n < NCdim; ++n) out[((size_t)b * Ndim + nn) * NCdim + n] = acc[n] + ob[n];
    }
}

// ---------------------------------------------------------------------------
extern "C" void kernel_launch(void* const* d_in, const int* in_sizes, int n_in,
                              void* d_out, int out_size, void* d_ws, size_t ws_size,
                              hipStream_t stream)
{
    const float*  features  = (const float*)d_in[0];
    const int*    s_mask    = (const int*)  d_in[1];
    const float*  entro     = (const float*)d_in[2];
    const float*  alpha     = (const float*)d_in[3];
    const float*  threshold = (const float*)d_in[4];
    const float*  fc1_w     = (const float*)d_in[5];
    const float*  fc1_b     = (const float*)d_in[6];
    const float*  gat_w     = (const float*)d_in[7];
    const float*  gat_b     = (const float*)d_in[8];
    const float*  wr0       = (const float*)d_in[9];
    const float*  wr1       = (const float*)d_in[10];
    const float*  enhance_w = (const float*)d_in[11];
    const float*  enhance_b = (const float*)d_in[12];
    const float*  prelu_a   = (const float*)d_in[13];
    const float*  lstm_w_ih = (const float*)d_in[14];
    const float*  lstm_w_hh = (const float*)d_in[15];
    const float*  lstm_b_ih = (const float*)d_in[16];
    const float*  lstm_b_hh = (const float*)d_in[17];
    const float*  mlp_w0    = (const float*)d_in[18];
    const float*  mlp_b0    = (const float*)d_in[19];
    const float*  mlp_a0    = (const float*)d_in[20];
    const float*  mlp_w1    = (const float*)d_in[21];
    const float*  mlp_b1    = (const float*)d_in[22];
    const float*  mlp_a1    = (const float*)d_in[23];
    const float*  out_w     = (const float*)d_in[24];
    const float*  out_b     = (const float*)d_in[25];
    float* out = (float*)d_out;
    char* ws = (char*)d_ws;

    // ---- workspace layout (bytes, all 256-aligned) ----
    uint8_t* adj   = (uint8_t*)(ws + 0);               //  2,359,296
    float*   invn  = (float*)(ws + 2359296);           //     98,304
    float*   qbuf  = (float*)(ws + 2457600);           //     98,304
    float*   kbuf  = (float*)(ws + 2555904);           //     98,304
    float*   G     = (float*)(ws + 2654208);           //  2,457,600
    float*   hbuf  = (float*)(ws + 5111808);           //    614,400
    float*   cbuf  = (float*)(ws + 5726208);           //    614,400
    float*   Hcat  = (float*)(ws + 6340608);           // 88,473,600  (ROWS,900) n-major
    float*   Hlstm = (float*)(ws + 94814208);          // 58,982,400  (ROWS,600) n-major
    char*    scr   = ws + 153796608;                   // scratch region
    // scratch aliases (phase-disjoint lifetimes):
    float*   V0    = (float*)scr;                      // 29,491,200  (GAT)
    float*   V1    = (float*)(scr + 29491200);         // 29,491,200  (GAT)
    float*   x1    = (float*)scr;                      // 29,491,200  (MLP)
    float*   x2    = (float*)(scr + 29491200);         // 29,491,200  (MLP)

    // choose time-chunk T by available workspace
    const size_t base = 153796608;
    int T;
    if      (ws_size >= base + 336592896ull) T = 96;   // 490.4 MB total
    else if (ws_size >= base + 112197632ull) T = 32;   // 266.0 MB
    else if (ws_size >= base +  58982400ull) T = 16;   // 212.8 MB
    else return;                                       // visible failure, no OOB
    float* featC = (float*)scr;                                    // (T*B,1024)
    float* zinC  = (float*)(scr + (size_t)T * Bdim * Edim * 4);    // (T*B,2400)

    // 1) row norms + adjacency (b-major on features)
    norm_kernel<<<ROWS / 4, 256, 0, stream>>>(features, invn);
    simadj_kernel<<<Bdim, 256, 0, stream>>>(features, invn, entro, alpha, threshold, adj);

    // 2) H0 = prelu(features @ fc1_w^T + fc1_b) into Hcat[:, 0:300] (n-major rows)
    gemm_tn<1,0><<<dim3(ROWS/64, 5), 256, 0, stream>>>(
        features, Edim, 255, Ndim, 8, 1, 0,
        fc1_w, Edim, Hcat, GDdim, ROWS, HDdim, Edim, fc1_b, nullptr, prelu_a);

    // 3) GAT layers
    for (int l = 0; l < Ldim; ++l) {
        const float* Hsrc = Hcat + l * HDdim;
        qk_kernel<<<ROWS / 4, 256, 0, stream>>>(Hsrc, gat_w + l * 2 * HDdim, qbuf, kbuf);
        gemm_tn<0,0><<<dim3(ROWS/64, 5), 256, 0, stream>>>(
            Hsrc, GDdim, IDP, wr0 + (size_t)l * HDdim * HDdim, HDdim,
            V0, HDdim, ROWS, HDdim, HDdim, nullptr, nullptr, nullptr);
        gemm_tn<0,0><<<dim3(ROWS/64, 5), 256, 0, stream>>>(
            Hsrc, GDdim, IDP, wr1 + (size_t)l * HDdim * HDdim, HDdim,
            V1, HDdim, ROWS, HDdim, HDdim, nullptr, nullptr, nullptr);
        gat_attn_kernel<<<ROWS, 128, 0, stream>>>(
            qbuf, kbuf, adj, s_mask, V0, V1, gat_b + l, Hcat + (l + 1) * HDdim);
    }

    // 4) init h, c
    zero_hc_kernel<<<(Bdim * LHdim + 255) / 256, 256, 0, stream>>>(hbuf, cbuf, Bdim * LHdim);

    // 5) chunked: enhance -> zin -> LSTM steps
    for (int t0 = 0; t0 < Ndim; t0 += T) {
        int Tc = (t0 + T <= Ndim) ? T : (Ndim - t0);
        int Mc = Tc * Bdim;
        // featC = prelu(features[perm] @ enhance_w^T + enhance_b)
        gemm_tn<1,0><<<dim3(Mc/64, 16), 256, 0, stream>>>(
            features, Edim, 255, Ndim, 8, 1, t0,
            enhance_w, Edim, featC, Edim, Mc, Edim, Edim, enhance_b, nullptr, prelu_a);
        // zinC = featC @ Wih[:, :1024]^T + b_ih + b_hh
        gemm_tn<0,0><<<dim3(Mc/64, 38), 256, 0, stream>>>(
            featC, Edim, IDP, lstm_w_ih, Edim + GDdim,
            zinC, 4 * LHdim, Mc, 4 * LHdim, Edim, lstm_b_ih, lstm_b_hh, nullptr);
        // zinC += Hcat[chunk rows] @ Wih[:, 1024:]^T
        gemm_tn<0,1><<<dim3(Mc/64, 38), 256, 0, stream>>>(
            Hcat + (size_t)t0 * Bdim * GDdim, GDdim, IDP, lstm_w_ih + Edim, Edim + GDdim,
            zinC, 4 * LHdim, Mc, 4 * LHdim, GDdim, nullptr, nullptr, nullptr);
        // LSTM steps in this chunk
        for (int tl = 0; tl < Tc; ++tl) {
            gemm_tn<0,0><<<dim3(Bdim/64, 38), 256, 0, stream>>>(
                hbuf, LHdim, IDP, lstm_w_hh, LHdim,
                G, 4 * LHdim, Bdim, 4 * LHdim, LHdim, nullptr, nullptr, nullptr);
            lstm_cell_kernel<<<(Bdim * LHdim + 255) / 256, 256, 0, stream>>>(
                G, zinC + (size_t)tl * Bdim * 4 * LHdim, hbuf, cbuf,
                Hlstm + (size_t)(t0 + tl) * Bdim * LHdim);
        }
    }

    // 6) MLP head (n-major rows throughout; out_kernel de-permutes)
    gemm_tn<1,0><<<dim3(ROWS/64, 5), 256, 0, stream>>>(
        Hlstm, LHdim, IDP, mlp_w0, LHdim, x1, HDdim, ROWS, HDdim, LHdim, mlp_b0, nullptr, mlp_a0);
    gemm_tn<1,0><<<dim3(ROWS/64, 5), 256, 0, stream>>>(
        x1, HDdim, IDP, mlp_w1, HDdim, x2, HDdim, ROWS, HDdim, HDdim, mlp_b1, nullptr, mlp_a1);
    out_kernel<<<ROWS / 4, 256, 0, stream>>>(x2, out_w, out_b, out);
}